// Round 1
// baseline (1834.417 us; speedup 1.0000x reference)
//
#include <hip/hip_runtime.h>

#define B_ 32
#define NP 196
#define PD 768
#define DM 512
#define NC 1000
#define MAT (NP*NP)
#define NT14 14

// ---------------- patchify + LN + pos ----------------
__global__ __launch_bounds__(256) void k_patchify(
    const float* __restrict__ img, const float* __restrict__ g,
    const float* __restrict__ be, const float* __restrict__ pos,
    float* __restrict__ x) {
  int bn = blockIdx.x;
  int b = bn / NP, n = bn % NP;
  int gh = n / 14, gw = n % 14;
  int t = threadIdx.x;
  float vals[3]; float s = 0.f, ss = 0.f;
  #pragma unroll
  for (int k = 0; k < 3; ++k) {
    int e = t + (k << 8);
    int inner = e & 255;
    int ph = inner >> 4, pw = inner & 15;
    float v = img[((b*3 + k)*224 + gh*16 + ph)*224 + gw*16 + pw];
    vals[k] = v; s += v; ss += v*v;
  }
  __shared__ float rb[8];
  for (int o = 32; o; o >>= 1) { s += __shfl_down(s,o); ss += __shfl_down(ss,o); }
  if ((t & 63) == 0) { rb[t>>6] = s; rb[4+(t>>6)] = ss; }
  __syncthreads();
  float S = rb[0]+rb[1]+rb[2]+rb[3], SS = rb[4]+rb[5]+rb[6]+rb[7];
  float mu = S * (1.f/768.f);
  float var = SS * (1.f/768.f) - mu*mu;
  float inv = rsqrtf(var + 1e-5f);
  #pragma unroll
  for (int k = 0; k < 3; ++k) {
    int e = t + (k << 8);
    x[(size_t)bn*PD + e] = (vals[k]-mu)*inv*g[e] + be[e] + pos[n*PD + e];
  }
}

// ---------------- GEMM M=6272 K=768 N=512 (64x64 tile, 4x4/thread) ----------------
__global__ __launch_bounds__(256) void k_gemm768(
    const float* __restrict__ A, const float* __restrict__ W,
    const float* __restrict__ bias, float* __restrict__ out) {
  __shared__ __align__(16) float As[16][68];
  __shared__ __align__(16) float Bs[16][64];
  int n0 = blockIdx.x * 64, m0 = blockIdx.y * 64;
  int t = threadIdx.x, tx = t & 15, ty = t >> 4;
  int alr = t >> 2, alc = (t & 3) << 2;   // A tile: 64 rows x 16 k
  int blr = t >> 4, blc = (t & 15) << 2;  // W tile: 16 k x 64 n
  float acc[4][4] = {};
  for (int k0 = 0; k0 < 768; k0 += 16) {
    float4 av = *reinterpret_cast<const float4*>(&A[(size_t)(m0+alr)*768 + k0 + alc]);
    float4 bv = *reinterpret_cast<const float4*>(&W[(size_t)(k0+blr)*512 + n0 + blc]);
    As[alc+0][alr] = av.x; As[alc+1][alr] = av.y;
    As[alc+2][alr] = av.z; As[alc+3][alr] = av.w;
    *reinterpret_cast<float4*>(&Bs[blr][blc]) = bv;
    __syncthreads();
    #pragma unroll
    for (int kt = 0; kt < 16; ++kt) {
      float a4[4], b4[4];
      *reinterpret_cast<float4*>(a4) = *reinterpret_cast<const float4*>(&As[kt][ty<<2]);
      *reinterpret_cast<float4*>(b4) = *reinterpret_cast<const float4*>(&Bs[kt][tx<<2]);
      #pragma unroll
      for (int i = 0; i < 4; ++i)
        #pragma unroll
        for (int j = 0; j < 4; ++j) acc[i][j] += a4[i]*b4[j];
    }
    __syncthreads();
  }
  float4 bvv = *reinterpret_cast<const float4*>(&bias[n0 + (tx<<2)]);
  float bb4[4] = {bvv.x, bvv.y, bvv.z, bvv.w};
  #pragma unroll
  for (int i = 0; i < 4; ++i) {
    float4 o;
    o.x = acc[i][0]+bb4[0]; o.y = acc[i][1]+bb4[1];
    o.z = acc[i][2]+bb4[2]; o.w = acc[i][3]+bb4[3];
    *reinterpret_cast<float4*>(&out[(size_t)(m0+(ty<<2)+i)*512 + n0 + (tx<<2)]) = o;
  }
}

// ---------------- row LayerNorm over 512 (+scale) ----------------
__global__ __launch_bounds__(256) void k_lnrow(
    float* __restrict__ X, const float* __restrict__ g,
    const float* __restrict__ be, float scale) {
  int r = blockIdx.x, t = threadIdx.x;
  float v0 = X[(size_t)r*512 + t], v1 = X[(size_t)r*512 + 256 + t];
  float s = v0+v1, ss = v0*v0+v1*v1;
  __shared__ float rb[8];
  for (int o = 32; o; o >>= 1) { s += __shfl_down(s,o); ss += __shfl_down(ss,o); }
  if ((t&63)==0) { rb[t>>6]=s; rb[4+(t>>6)]=ss; }
  __syncthreads();
  float S = rb[0]+rb[1]+rb[2]+rb[3], SS = rb[4]+rb[5]+rb[6]+rb[7];
  float mu = S*(1.f/512.f), var = SS*(1.f/512.f)-mu*mu;
  float inv = rsqrtf(var+1e-5f);
  X[(size_t)r*512+t]     = ((v0-mu)*inv*g[t]+be[t])*scale;
  X[(size_t)r*512+256+t] = ((v1-mu)*inv*g[t+256]+be[t+256])*scale;
}

// ---------------- batched NT gemm: out[b,r,c] = alpha*sum_d X[b,r,d]Y[b,c,d] + diag + const ----------------
__global__ __launch_bounds__(256) void k_bgemm_nt(
    const float* __restrict__ X, const float* __restrict__ Y,
    float* __restrict__ out, float alpha, float diagAdd, float cAdd) {
  int b = blockIdx.z;
  int c0 = blockIdx.x * 32, r0 = blockIdx.y * 32;
  __shared__ __align__(16) float Xs[32][36];
  __shared__ __align__(16) float Ys[32][36];
  int t = threadIdx.x, tx = t & 15, ty = t >> 4;
  int lr = t >> 3, lk = (t & 7) << 2;
  const float* Xb = X + (size_t)b*NP*512;
  const float* Yb = Y + (size_t)b*NP*512;
  float acc[2][2] = {};
  int xr = min(r0 + lr, NP-1), yr = min(c0 + lr, NP-1);
  for (int k0 = 0; k0 < 512; k0 += 32) {
    *reinterpret_cast<float4*>(&Xs[lr][lk]) =
        *reinterpret_cast<const float4*>(&Xb[(size_t)xr*512 + k0 + lk]);
    *reinterpret_cast<float4*>(&Ys[lr][lk]) =
        *reinterpret_cast<const float4*>(&Yb[(size_t)yr*512 + k0 + lk]);
    __syncthreads();
    #pragma unroll
    for (int kt = 0; kt < 32; ++kt) {
      float x0 = Xs[ty*2][kt], x1 = Xs[ty*2+1][kt];
      float y0 = Ys[tx*2][kt], y1 = Ys[tx*2+1][kt];
      acc[0][0] += x0*y0; acc[0][1] += x0*y1;
      acc[1][0] += x1*y0; acc[1][1] += x1*y1;
    }
    __syncthreads();
  }
  #pragma unroll
  for (int i = 0; i < 2; ++i) {
    int r = r0 + ty*2 + i; if (r >= NP) continue;
    #pragma unroll
    for (int j = 0; j < 2; ++j) {
      int c = c0 + tx*2 + j; if (c >= NP) continue;
      out[((size_t)b*NP + r)*NP + c] = alpha*acc[i][j] + cAdd + (r==c ? diagAdd : 0.f);
    }
  }
}

// ---------------- Newton-Schulz init: ninf bound + X0 = c*I ----------------
__global__ __launch_bounds__(256) void k_nsinit(
    const float* __restrict__ A, float* __restrict__ X) {
  int b = blockIdx.x, t = threadIdx.x;
  const float* Ab = A + (size_t)b*MAT;
  __shared__ float sm[256];
  float lm = 0.f;
  if (t < NP) {
    float s = 0.f;
    for (int j = 0; j < NP; ++j) {
      float v = Ab[t*NP + j];
      if (j == t) v -= 1.f;
      s += fabsf(v);
    }
    lm = s;
  }
  sm[t] = lm; __syncthreads();
  for (int o = 128; o; o >>= 1) { if (t < o) sm[t] = fmaxf(sm[t], sm[t+o]); __syncthreads(); }
  float cc = 2.f / (2.f + sm[0]);
  float* Xb = X + (size_t)b*MAT;
  for (int idx = t; idx < MAT; idx += 256)
    Xb[idx] = (idx % (NP+1) == 0) ? cc : 0.f;
}

// ---------------- batched NN gemm (196x196x196): out = alpha*L@R (+ addScale*Add) ----------------
__global__ __launch_bounds__(256) void k_bgemm_nn(
    const float* __restrict__ L, const float* __restrict__ R,
    float* __restrict__ out, float alpha,
    const float* __restrict__ Add, float addScale) {
  int b = blockIdx.z;
  int c0 = blockIdx.x * 64, r0 = blockIdx.y * 64;
  __shared__ __align__(16) float Ls[16][68];
  __shared__ __align__(16) float Rs[16][64];
  int t = threadIdx.x, tx = t & 15, ty = t >> 4;
  int alr = t >> 2, alc = (t & 3) << 2;   // L: 64 rows x 16 k
  int blr = t >> 4, blc = (t & 15) << 2;  // R: 16 k x 64 cols
  const float* Lb = L + (size_t)b*MAT;
  const float* Rb = R + (size_t)b*MAT;
  float acc[4][4] = {};
  int lrow = min(r0 + alr, NP-1);
  for (int k0 = 0; k0 < NP; k0 += 16) {
    float4 lv = {0.f,0.f,0.f,0.f};
    if (k0 + alc < NP) lv = *reinterpret_cast<const float4*>(&Lb[(size_t)lrow*NP + k0 + alc]);
    float4 rv = {0.f,0.f,0.f,0.f};
    if (k0 + blr < NP) rv = *reinterpret_cast<const float4*>(&Rb[(size_t)(k0+blr)*NP + c0 + blc]);
    Ls[alc+0][alr] = lv.x; Ls[alc+1][alr] = lv.y;
    Ls[alc+2][alr] = lv.z; Ls[alc+3][alr] = lv.w;
    *reinterpret_cast<float4*>(&Rs[blr][blc]) = rv;
    __syncthreads();
    #pragma unroll
    for (int kt = 0; kt < 16; ++kt) {
      float a4[4], b4[4];
      *reinterpret_cast<float4*>(a4) = *reinterpret_cast<const float4*>(&Ls[kt][ty<<2]);
      *reinterpret_cast<float4*>(b4) = *reinterpret_cast<const float4*>(&Rs[kt][tx<<2]);
      #pragma unroll
      for (int i = 0; i < 4; ++i)
        #pragma unroll
        for (int j = 0; j < 4; ++j) acc[i][j] += a4[i]*b4[j];
    }
    __syncthreads();
  }
  #pragma unroll
  for (int i = 0; i < 4; ++i) {
    int r = r0 + (ty<<2) + i; if (r >= NP) continue;
    #pragma unroll
    for (int j = 0; j < 4; ++j) {
      int c = c0 + (tx<<2) + j; if (c >= NP) continue;
      float v = alpha * acc[i][j];
      if (Add) v += addScale * Add[((size_t)b*NP + r)*NP + c];
      out[((size_t)b*NP + r)*NP + c] = v;
    }
  }
}

// ---------------- fused 50-iteration ADMM (block-local rows) + coeff reduction ----------------
__global__ __launch_bounds__(256) void k_admm(
    const float* __restrict__ Minv, const float* __restrict__ P,
    float* __restrict__ w) {
  int tile = blockIdx.x, b = blockIdx.y;
  int n0 = tile * NT14;
  int t = threadIdx.x;
  __shared__ float zs[NT14][196];
  __shared__ float us[NT14][196];
  __shared__ float ps[NT14][196];
  __shared__ __align__(16) float rs[NT14][196];
  __shared__ float ssum[NT14];
  const float* Mb = Minv + (size_t)b*MAT;
  const float* Pb = P + ((size_t)b*NP + n0)*NP;
  for (int n = 0; n < NT14; ++n)
    for (int j = t; j < NP; j += 256) {
      ps[n][j] = Pb[n*NP + j];
      zs[n][j] = 0.f; us[n][j] = 0.f;
    }
  __syncthreads();
  float acc[NT14];
  for (int it = 0; it < 50; ++it) {
    // rhs = (z - u) - p  (rho = 1), column-local per thread
    if (t < NP) {
      #pragma unroll
      for (int n = 0; n < NT14; ++n)
        rs[n][t] = zs[n][t] - us[n][t] - ps[n][t];
    }
    __syncthreads();
    if (t < NP) {
      #pragma unroll
      for (int n = 0; n < NT14; ++n) acc[n] = 0.f;
      #pragma unroll 2
      for (int jq = 0; jq < 49; ++jq) {
        float m0 = Mb[(size_t)(jq*4+0)*NP + t];
        float m1 = Mb[(size_t)(jq*4+1)*NP + t];
        float m2 = Mb[(size_t)(jq*4+2)*NP + t];
        float m3 = Mb[(size_t)(jq*4+3)*NP + t];
        #pragma unroll
        for (int n = 0; n < NT14; ++n) {
          float4 r4 = *reinterpret_cast<const float4*>(&rs[n][jq<<2]);
          acc[n] += m0*r4.x + m1*r4.y + m2*r4.z + m3*r4.w;
        }
      }
      #pragma unroll
      for (int n = 0; n < NT14; ++n) {
        float u = us[n][t];
        float xpu = acc[n] + u;
        float z = fminf(fmaxf(xpu, 0.f), 1.f);
        zs[n][t] = z;
        us[n][t] = xpu - z;
      }
    }
    __syncthreads();
  }
  // coeffs = z / (sum|z| + 1e-10); accumulate w[b,m] = mean_n coeffs[n,m]
  if (t < NT14) {
    float s = 0.f;
    for (int j = 0; j < NP; ++j) s += zs[t][j];   // z >= 0 after clip
    ssum[t] = 1.f / (s + 1e-10f);
  }
  __syncthreads();
  if (t < NP) {
    float a2 = 0.f;
    #pragma unroll
    for (int n = 0; n < NT14; ++n) a2 += zs[n][t] * ssum[n];
    atomicAdd(&w[b*NP + t], a2 * (1.f/196.f));
  }
}

// ---------------- pooled[b,d] = sum_m w[b,m] V[b,m,d] ----------------
__global__ __launch_bounds__(256) void k_pooled(
    const float* __restrict__ w, const float* __restrict__ V,
    float* __restrict__ pooled) {
  int b = blockIdx.y, t = threadIdx.x;
  int d = blockIdx.x * 256 + t;
  __shared__ float ws_[NP];
  if (t < NP) ws_[t] = w[b*NP + t];
  __syncthreads();
  float acc = 0.f;
  for (int m = 0; m < NP; ++m)
    acc += ws_[m] * V[((size_t)b*NP + m)*512 + d];
  pooled[(size_t)b*512 + d] = acc;
}

// ---------------- LN + 512x1000 head + softmax ----------------
__global__ __launch_bounds__(256) void k_head(
    const float* __restrict__ pooled, const float* __restrict__ g,
    const float* __restrict__ be, const float* __restrict__ Wm,
    const float* __restrict__ bm, float* __restrict__ out) {
  int b = blockIdx.x, t = threadIdx.x;
  __shared__ float pl[512];
  __shared__ float rb[8];
  float v0 = pooled[(size_t)b*512 + t], v1 = pooled[(size_t)b*512 + 256 + t];
  float s = v0+v1, ss = v0*v0+v1*v1;
  for (int o = 32; o; o >>= 1) { s += __shfl_down(s,o); ss += __shfl_down(ss,o); }
  if ((t&63)==0) { rb[t>>6]=s; rb[4+(t>>6)]=ss; }
  __syncthreads();
  float S = rb[0]+rb[1]+rb[2]+rb[3], SS = rb[4]+rb[5]+rb[6]+rb[7];
  float mu = S*(1.f/512.f), var = SS*(1.f/512.f)-mu*mu, inv = rsqrtf(var+1e-5f);
  pl[t] = (v0-mu)*inv*g[t] + be[t];
  pl[t+256] = (v1-mu)*inv*g[t+256] + be[t+256];
  __syncthreads();
  float lg[4];
  #pragma unroll
  for (int q = 0; q < 4; ++q) {
    int c = t + (q<<8);
    float a = -1e30f;
    if (c < NC) {
      a = bm[c];
      #pragma unroll 8
      for (int k = 0; k < 512; ++k) a += pl[k]*Wm[(size_t)k*NC + c];
    }
    lg[q] = a;
  }
  float mx = fmaxf(fmaxf(lg[0],lg[1]), fmaxf(lg[2],lg[3]));
  for (int o = 32; o; o >>= 1) mx = fmaxf(mx, __shfl_down(mx,o));
  __syncthreads();
  if ((t&63)==0) rb[t>>6] = mx;
  __syncthreads();
  float MX = fmaxf(fmaxf(rb[0],rb[1]), fmaxf(rb[2],rb[3]));
  float es = 0.f, ev[4];
  #pragma unroll
  for (int q = 0; q < 4; ++q) {
    int c = t + (q<<8);
    ev[q] = (c < NC) ? __expf(lg[q]-MX) : 0.f;
    es += ev[q];
  }
  for (int o = 32; o; o >>= 1) es += __shfl_down(es,o);
  __syncthreads();
  if ((t&63)==0) rb[4+(t>>6)] = es;
  __syncthreads();
  float SUM = rb[4]+rb[5]+rb[6]+rb[7];
  float rinv = 1.f/SUM;
  #pragma unroll
  for (int q = 0; q < 4; ++q) {
    int c = t + (q<<8);
    if (c < NC) out[(size_t)b*NC + c] = ev[q]*rinv;
  }
}

extern "C" void kernel_launch(void* const* d_in, const int* in_sizes, int n_in,
                              void* d_out, int out_size, void* d_ws, size_t ws_size,
                              hipStream_t stream) {
  const float* img = (const float*)d_in[0];
  const float* lpg = (const float*)d_in[1];
  const float* lpb = (const float*)d_in[2];
  const float* wqw = (const float*)d_in[3];
  const float* wqb = (const float*)d_in[4];
  const float* lqg = (const float*)d_in[5];
  const float* lqb = (const float*)d_in[6];
  const float* wvw = (const float*)d_in[7];
  const float* wvb = (const float*)d_in[8];
  const float* lvg = (const float*)d_in[9];
  const float* lvb = (const float*)d_in[10];
  const float* pos = (const float*)d_in[11];
  const float* mlg = (const float*)d_in[12];
  const float* mlb = (const float*)d_in[13];
  const float* mw  = (const float*)d_in[14];
  const float* mb  = (const float*)d_in[15];
  float* outp = (float*)d_out;

  float* ws = (float*)d_ws;
  size_t off = 0;
  float* x  = ws + off;      off += (size_t)B_*NP*PD;
  float* q  = ws + off;      off += (size_t)B_*NP*DM;
  float* v  = ws + off;      off += (size_t)B_*NP*DM;
  size_t matp = (size_t)B_*MAT + 128;  // +pad for benign column-overrun reads
  float* A  = ws + off;      off += matp;
  float* p  = ws + off;      off += matp;
  float* Xa = ws + off;      off += matp;
  float* Xb = ws + off;      off += matp;
  float* T  = ws + off;      off += matp;
  float* w  = ws + off;      off += (size_t)B_*NP;
  float* pooled = ws + off;  off += (size_t)B_*DM;
  if (ws_size < off * sizeof(float)) return;  // workspace too small -> fail loudly

  k_patchify<<<dim3(B_*NP), 256, 0, stream>>>(img, lpg, lpb, pos, x);
  k_gemm768<<<dim3(8, 98), 256, 0, stream>>>(x, wqw, wqb, q);
  k_gemm768<<<dim3(8, 98), 256, 0, stream>>>(x, wvw, wvb, v);
  k_lnrow<<<dim3(B_*NP), 256, 0, stream>>>(q, lqg, lqb, 1.0f);
  k_lnrow<<<dim3(B_*NP), 256, 0, stream>>>(v, lvg, lvb, 1.0f/196.0f);
  // A = 2 V V^T + I ;  p = -2 Q V^T + 1/196
  k_bgemm_nt<<<dim3(7,7,B_), 256, 0, stream>>>(v, v, A, 2.0f, 1.0f, 0.0f);
  k_bgemm_nt<<<dim3(7,7,B_), 256, 0, stream>>>(q, v, p, -2.0f, 0.0f, 1.0f/196.0f);
  // Minv via Newton-Schulz (A is SPD, lambda in [1, 1+ninf] -> guaranteed contraction)
  k_nsinit<<<dim3(B_), 256, 0, stream>>>(A, Xa);
  float* cur = Xa; float* nxt = Xb;
  for (int it = 0; it < 6; ++it) {
    k_bgemm_nn<<<dim3(4,4,B_), 256, 0, stream>>>(A, cur, T, 1.0f, nullptr, 0.0f);
    k_bgemm_nn<<<dim3(4,4,B_), 256, 0, stream>>>(cur, T, nxt, -1.0f, cur, 2.0f);
    float* tmp = cur; cur = nxt; nxt = tmp;
  }
  hipMemsetAsync(w, 0, (size_t)B_*NP*sizeof(float), stream);
  k_admm<<<dim3(NP/NT14, B_), 256, 0, stream>>>(cur, p, w);
  k_pooled<<<dim3(2, B_), 256, 0, stream>>>(w, v, pooled);
  k_head<<<dim3(B_), 256, 0, stream>>>(pooled, mlg, mlb, mw, mb, outp);
}

// Round 2
// 1341.909 us; speedup vs baseline: 1.3670x; 1.3670x over previous
//
#include <hip/hip_runtime.h>

#define B_ 32
#define NP 196
#define PD 768
#define DM 512
#define NC 1000
#define MAT (NP*NP)

// ---------------- patchify + LN + pos ----------------
__global__ __launch_bounds__(256) void k_patchify(
    const float* __restrict__ img, const float* __restrict__ g,
    const float* __restrict__ be, const float* __restrict__ pos,
    float* __restrict__ x) {
  int bn = blockIdx.x;
  int b = bn / NP, n = bn % NP;
  int gh = n / 14, gw = n % 14;
  int t = threadIdx.x;
  float vals[3]; float s = 0.f, ss = 0.f;
  #pragma unroll
  for (int k = 0; k < 3; ++k) {
    int e = t + (k << 8);
    int inner = e & 255;
    int ph = inner >> 4, pw = inner & 15;
    float v = img[((b*3 + k)*224 + gh*16 + ph)*224 + gw*16 + pw];
    vals[k] = v; s += v; ss += v*v;
  }
  __shared__ float rb[8];
  for (int o = 32; o; o >>= 1) { s += __shfl_down(s,o); ss += __shfl_down(ss,o); }
  if ((t & 63) == 0) { rb[t>>6] = s; rb[4+(t>>6)] = ss; }
  __syncthreads();
  float S = rb[0]+rb[1]+rb[2]+rb[3], SS = rb[4]+rb[5]+rb[6]+rb[7];
  float mu = S * (1.f/768.f);
  float var = SS * (1.f/768.f) - mu*mu;
  float inv = rsqrtf(var + 1e-5f);
  #pragma unroll
  for (int k = 0; k < 3; ++k) {
    int e = t + (k << 8);
    x[(size_t)bn*PD + e] = (vals[k]-mu)*inv*g[e] + be[e] + pos[n*PD + e];
  }
}

// ---------------- GEMM M=6272 K=768 N=512 (64x64 tile, 4x4/thread) ----------------
__global__ __launch_bounds__(256) void k_gemm768(
    const float* __restrict__ A, const float* __restrict__ W,
    const float* __restrict__ bias, float* __restrict__ out) {
  __shared__ __align__(16) float As[16][68];
  __shared__ __align__(16) float Bs[16][64];
  int n0 = blockIdx.x * 64, m0 = blockIdx.y * 64;
  int t = threadIdx.x, tx = t & 15, ty = t >> 4;
  int alr = t >> 2, alc = (t & 3) << 2;   // A tile: 64 rows x 16 k
  int blr = t >> 4, blc = (t & 15) << 2;  // W tile: 16 k x 64 n
  float acc[4][4] = {};
  for (int k0 = 0; k0 < 768; k0 += 16) {
    float4 av = *reinterpret_cast<const float4*>(&A[(size_t)(m0+alr)*768 + k0 + alc]);
    float4 bv = *reinterpret_cast<const float4*>(&W[(size_t)(k0+blr)*512 + n0 + blc]);
    As[alc+0][alr] = av.x; As[alc+1][alr] = av.y;
    As[alc+2][alr] = av.z; As[alc+3][alr] = av.w;
    *reinterpret_cast<float4*>(&Bs[blr][blc]) = bv;
    __syncthreads();
    #pragma unroll
    for (int kt = 0; kt < 16; ++kt) {
      float a4[4], b4[4];
      *reinterpret_cast<float4*>(a4) = *reinterpret_cast<const float4*>(&As[kt][ty<<2]);
      *reinterpret_cast<float4*>(b4) = *reinterpret_cast<const float4*>(&Bs[kt][tx<<2]);
      #pragma unroll
      for (int i = 0; i < 4; ++i)
        #pragma unroll
        for (int j = 0; j < 4; ++j) acc[i][j] += a4[i]*b4[j];
    }
    __syncthreads();
  }
  float4 bvv = *reinterpret_cast<const float4*>(&bias[n0 + (tx<<2)]);
  float bb4[4] = {bvv.x, bvv.y, bvv.z, bvv.w};
  #pragma unroll
  for (int i = 0; i < 4; ++i) {
    float4 o;
    o.x = acc[i][0]+bb4[0]; o.y = acc[i][1]+bb4[1];
    o.z = acc[i][2]+bb4[2]; o.w = acc[i][3]+bb4[3];
    *reinterpret_cast<float4*>(&out[(size_t)(m0+(ty<<2)+i)*512 + n0 + (tx<<2)]) = o;
  }
}

// ---------------- row LayerNorm over 512 (+scale) ----------------
__global__ __launch_bounds__(256) void k_lnrow(
    float* __restrict__ X, const float* __restrict__ g,
    const float* __restrict__ be, float scale) {
  int r = blockIdx.x, t = threadIdx.x;
  float v0 = X[(size_t)r*512 + t], v1 = X[(size_t)r*512 + 256 + t];
  float s = v0+v1, ss = v0*v0+v1*v1;
  __shared__ float rb[8];
  for (int o = 32; o; o >>= 1) { s += __shfl_down(s,o); ss += __shfl_down(ss,o); }
  if ((t&63)==0) { rb[t>>6]=s; rb[4+(t>>6)]=ss; }
  __syncthreads();
  float S = rb[0]+rb[1]+rb[2]+rb[3], SS = rb[4]+rb[5]+rb[6]+rb[7];
  float mu = S*(1.f/512.f), var = SS*(1.f/512.f)-mu*mu;
  float inv = rsqrtf(var+1e-5f);
  X[(size_t)r*512+t]     = ((v0-mu)*inv*g[t]+be[t])*scale;
  X[(size_t)r*512+256+t] = ((v1-mu)*inv*g[t+256]+be[t+256])*scale;
}

// ---------------- batched NT gemm: out[b,r,c] = alpha*sum_d X[b,r,d]Y[b,c,d] + diag + const ----------------
__global__ __launch_bounds__(256) void k_bgemm_nt(
    const float* __restrict__ X, const float* __restrict__ Y,
    float* __restrict__ out, float alpha, float diagAdd, float cAdd) {
  int b = blockIdx.z;
  int c0 = blockIdx.x * 32, r0 = blockIdx.y * 32;
  __shared__ __align__(16) float Xs[32][36];
  __shared__ __align__(16) float Ys[32][36];
  int t = threadIdx.x, tx = t & 15, ty = t >> 4;
  int lr = t >> 3, lk = (t & 7) << 2;
  const float* Xb = X + (size_t)b*NP*512;
  const float* Yb = Y + (size_t)b*NP*512;
  float acc[2][2] = {};
  int xr = min(r0 + lr, NP-1), yr = min(c0 + lr, NP-1);
  for (int k0 = 0; k0 < 512; k0 += 32) {
    *reinterpret_cast<float4*>(&Xs[lr][lk]) =
        *reinterpret_cast<const float4*>(&Xb[(size_t)xr*512 + k0 + lk]);
    *reinterpret_cast<float4*>(&Ys[lr][lk]) =
        *reinterpret_cast<const float4*>(&Yb[(size_t)yr*512 + k0 + lk]);
    __syncthreads();
    #pragma unroll
    for (int kt = 0; kt < 32; ++kt) {
      float x0 = Xs[ty*2][kt], x1 = Xs[ty*2+1][kt];
      float y0 = Ys[tx*2][kt], y1 = Ys[tx*2+1][kt];
      acc[0][0] += x0*y0; acc[0][1] += x0*y1;
      acc[1][0] += x1*y0; acc[1][1] += x1*y1;
    }
    __syncthreads();
  }
  #pragma unroll
  for (int i = 0; i < 2; ++i) {
    int r = r0 + ty*2 + i; if (r >= NP) continue;
    #pragma unroll
    for (int j = 0; j < 2; ++j) {
      int c = c0 + tx*2 + j; if (c >= NP) continue;
      out[((size_t)b*NP + r)*NP + c] = alpha*acc[i][j] + cAdd + (r==c ? diagAdd : 0.f);
    }
  }
}

// ---------------- Newton-Schulz init: ninf bound + X0 = c*I ----------------
__global__ __launch_bounds__(256) void k_nsinit(
    const float* __restrict__ A, float* __restrict__ X) {
  int b = blockIdx.x, t = threadIdx.x;
  const float* Ab = A + (size_t)b*MAT;
  __shared__ float sm[256];
  float lm = 0.f;
  if (t < NP) {
    float s = 0.f;
    for (int j = 0; j < NP; ++j) {
      float v = Ab[t*NP + j];
      if (j == t) v -= 1.f;
      s += fabsf(v);
    }
    lm = s;
  }
  sm[t] = lm; __syncthreads();
  for (int o = 128; o; o >>= 1) { if (t < o) sm[t] = fmaxf(sm[t], sm[t+o]); __syncthreads(); }
  float cc = 2.f / (2.f + sm[0]);
  float* Xb = X + (size_t)b*MAT;
  for (int idx = t; idx < MAT; idx += 256)
    Xb[idx] = (idx % (NP+1) == 0) ? cc : 0.f;
}

// ---------------- batched NN gemm (196x196x196): out = alpha*L@R (+ addScale*Add) ----------------
__global__ __launch_bounds__(256) void k_bgemm_nn(
    const float* __restrict__ L, const float* __restrict__ R,
    float* __restrict__ out, float alpha,
    const float* __restrict__ Add, float addScale) {
  int b = blockIdx.z;
  int c0 = blockIdx.x * 64, r0 = blockIdx.y * 64;
  __shared__ __align__(16) float Ls[16][68];
  __shared__ __align__(16) float Rs[16][64];
  int t = threadIdx.x, tx = t & 15, ty = t >> 4;
  int alr = t >> 2, alc = (t & 3) << 2;   // L: 64 rows x 16 k
  int blr = t >> 4, blc = (t & 15) << 2;  // R: 16 k x 64 cols
  const float* Lb = L + (size_t)b*MAT;
  const float* Rb = R + (size_t)b*MAT;
  float acc[4][4] = {};
  int lrow = min(r0 + alr, NP-1);
  for (int k0 = 0; k0 < NP; k0 += 16) {
    float4 lv = {0.f,0.f,0.f,0.f};
    if (k0 + alc < NP) lv = *reinterpret_cast<const float4*>(&Lb[(size_t)lrow*NP + k0 + alc]);
    float4 rv = {0.f,0.f,0.f,0.f};
    if (k0 + blr < NP) rv = *reinterpret_cast<const float4*>(&Rb[(size_t)(k0+blr)*NP + c0 + blc]);
    Ls[alc+0][alr] = lv.x; Ls[alc+1][alr] = lv.y;
    Ls[alc+2][alr] = lv.z; Ls[alc+3][alr] = lv.w;
    *reinterpret_cast<float4*>(&Rs[blr][blc]) = rv;
    __syncthreads();
    #pragma unroll
    for (int kt = 0; kt < 16; ++kt) {
      float a4[4], b4[4];
      *reinterpret_cast<float4*>(a4) = *reinterpret_cast<const float4*>(&Ls[kt][ty<<2]);
      *reinterpret_cast<float4*>(b4) = *reinterpret_cast<const float4*>(&Rs[kt][tx<<2]);
      #pragma unroll
      for (int i = 0; i < 4; ++i)
        #pragma unroll
        for (int j = 0; j < 4; ++j) acc[i][j] += a4[i]*b4[j];
    }
    __syncthreads();
  }
  #pragma unroll
  for (int i = 0; i < 4; ++i) {
    int r = r0 + (ty<<2) + i; if (r >= NP) continue;
    #pragma unroll
    for (int j = 0; j < 4; ++j) {
      int c = c0 + (tx<<2) + j; if (c >= NP) continue;
      float v = alpha * acc[i][j];
      if (Add) v += addScale * Add[((size_t)b*NP + r)*NP + c];
      out[((size_t)b*NP + r)*NP + c] = v;
    }
  }
}

// ---------------- fused 50-iter ADMM v2 ----------------
// Block: 256 thr = 8 ty-groups x 32 tx.  tx<28 own m in [7tx,7tx+7) (196=28*7 exact).
// ty owns j-range (8-way split of the 196-reduction) AND z/u/p for n in {2ty,2ty+1}.
// Minv rows read straight from global (L2), each element exactly once per block-iter.
// LDS carries only rhs broadcast (rsT) + j-partials (rp). z,u,p in registers.
__global__ __launch_bounds__(256, 2) void k_admm2(
    const float* __restrict__ Minv, const float* __restrict__ P,
    float* __restrict__ w) {
  int bid = blockIdx.x;
  int b = bid & 31;          // batch = id%32 -> XCD round-robin pins 4 batches/XCD L2
  int tile = bid >> 5;       // 13 tiles of 16 tokens (last: 192..207, 4 real)
  int n0 = tile * 16;
  int t = threadIdx.x;
  int tx = t & 31, ty = t >> 5;
  int wv = t >> 6;           // wave id 0..3
  bool act = (tx < 28);
  int m0 = 7 * tx;

  __shared__ __align__(16) float rsT[196][20];  // rhs transposed [j][n(16)], row=80B
  __shared__ float rp[4][16][200];              // per-wave j-partials

  const float* Mb = Minv + (size_t)b * MAT;
  const float* Pb = P + (size_t)b * MAT;

  // j-range per ty: ty<4 -> len 25, else 24 (wave pairs share length: no divergence)
  int jlen = (ty < 4) ? 25 : 24;
  int jstart = (ty < 4) ? 25 * ty : 100 + 24 * (ty - 4);

  float z[2][7], u[2][7], pr[2][7];
  #pragma unroll
  for (int i = 0; i < 2; ++i)
    #pragma unroll
    for (int k = 0; k < 7; ++k) { z[i][k] = 0.f; u[i][k] = 0.f; pr[i][k] = 0.f; }

  if (act) {
    #pragma unroll
    for (int i = 0; i < 2; ++i) {
      int ng = min(n0 + 2*ty + i, NP-1);   // pad-n duplicates token 195 (benign)
      const float* prow = Pb + (size_t)ng * NP + m0;
      #pragma unroll
      for (int k = 0; k < 7; ++k) pr[i][k] = prow[k];
      // initial rhs = z - u - p = -p
      #pragma unroll
      for (int k = 0; k < 7; ++k) rsT[m0 + k][2*ty + i] = -pr[i][k];
    }
  }
  __syncthreads();

  for (int it = 0; it < 50; ++it) {
    float acc[16][7];
    if (act) {
      #pragma unroll
      for (int n = 0; n < 16; ++n)
        #pragma unroll
        for (int k = 0; k < 7; ++k) acc[n][k] = 0.f;
      const float* mp = Mb + (size_t)jstart * NP + m0;
      for (int jj = 0; jj < jlen; ++jj) {
        int j = jstart + jj;
        float4 r0 = *reinterpret_cast<const float4*>(&rsT[j][0]);
        float4 r1 = *reinterpret_cast<const float4*>(&rsT[j][4]);
        float4 r2 = *reinterpret_cast<const float4*>(&rsT[j][8]);
        float4 r3 = *reinterpret_cast<const float4*>(&rsT[j][12]);
        float rr[16] = {r0.x,r0.y,r0.z,r0.w, r1.x,r1.y,r1.z,r1.w,
                        r2.x,r2.y,r2.z,r2.w, r3.x,r3.y,r3.z,r3.w};
        float mv[7];
        #pragma unroll
        for (int k = 0; k < 7; ++k) mv[k] = mp[k];
        #pragma unroll
        for (int n = 0; n < 16; ++n)
          #pragma unroll
          for (int k = 0; k < 7; ++k) acc[n][k] = fmaf(mv[k], rr[n], acc[n][k]);
        mp += NP;
      }
      // pair-reduce across wave halves (partner has same tx -> both active)
      #pragma unroll
      for (int n = 0; n < 16; ++n)
        #pragma unroll
        for (int k = 0; k < 7; ++k)
          acc[n][k] += __shfl_xor(acc[n][k], 32, 64);
      if ((t & 63) < 32) {
        #pragma unroll
        for (int n = 0; n < 16; ++n)
          #pragma unroll
          for (int k = 0; k < 7; ++k) rp[wv][n][m0 + k] = acc[n][k];
      }
    }
    __syncthreads();
    if (act) {
      #pragma unroll
      for (int i = 0; i < 2; ++i) {
        int n = 2*ty + i;
        #pragma unroll
        for (int k = 0; k < 7; ++k) {
          int m = m0 + k;
          float x = rp[0][n][m] + rp[1][n][m] + rp[2][n][m] + rp[3][n][m];
          float xpu = x + u[i][k];
          float zz = fminf(fmaxf(xpu, 0.f), 1.f);
          u[i][k] = xpu - zz;
          z[i][k] = zz;
          rsT[m][n] = zz - u[i][k] - pr[i][k];
        }
      }
    }
    __syncthreads();
  }

  // coeffs = z / (sum z + 1e-10); w[b][m] += mean_n coeffs
  float s0 = 0.f, s1 = 0.f;
  #pragma unroll
  for (int k = 0; k < 7; ++k) { s0 += z[0][k]; s1 += z[1][k]; }
  #pragma unroll
  for (int o = 16; o; o >>= 1) {   // butterfly within 32-half (idle lanes hold 0)
    s0 += __shfl_xor(s0, o, 64);
    s1 += __shfl_xor(s1, o, 64);
  }
  float inv0 = 1.f / (s0 + 1e-10f), inv1 = 1.f / (s1 + 1e-10f);
  if (n0 + 2*ty     >= NP) inv0 = 0.f;   // mask pad tokens
  if (n0 + 2*ty + 1 >= NP) inv1 = 0.f;
  if (act) {
    #pragma unroll
    for (int k = 0; k < 7; ++k) {
      float c = (z[0][k]*inv0 + z[1][k]*inv1) * (1.f/196.f);
      atomicAdd(&w[b*NP + m0 + k], c);
    }
  }
}

// ---------------- pooled[b,d] = sum_m w[b,m] V[b,m,d] ----------------
__global__ __launch_bounds__(256) void k_pooled(
    const float* __restrict__ w, const float* __restrict__ V,
    float* __restrict__ pooled) {
  int b = blockIdx.y, t = threadIdx.x;
  int d = blockIdx.x * 256 + t;
  __shared__ float ws_[NP];
  if (t < NP) ws_[t] = w[b*NP + t];
  __syncthreads();
  float acc = 0.f;
  for (int m = 0; m < NP; ++m)
    acc += ws_[m] * V[((size_t)b*NP + m)*512 + d];
  pooled[(size_t)b*512 + d] = acc;
}

// ---------------- LN + 512x1000 head + softmax ----------------
__global__ __launch_bounds__(256) void k_head(
    const float* __restrict__ pooled, const float* __restrict__ g,
    const float* __restrict__ be, const float* __restrict__ Wm,
    const float* __restrict__ bm, float* __restrict__ out) {
  int b = blockIdx.x, t = threadIdx.x;
  __shared__ float pl[512];
  __shared__ float rb[8];
  float v0 = pooled[(size_t)b*512 + t], v1 = pooled[(size_t)b*512 + 256 + t];
  float s = v0+v1, ss = v0*v0+v1*v1;
  for (int o = 32; o; o >>= 1) { s += __shfl_down(s,o); ss += __shfl_down(ss,o); }
  if ((t&63)==0) { rb[t>>6]=s; rb[4+(t>>6)]=ss; }
  __syncthreads();
  float S = rb[0]+rb[1]+rb[2]+rb[3], SS = rb[4]+rb[5]+rb[6]+rb[7];
  float mu = S*(1.f/512.f), var = SS*(1.f/512.f)-mu*mu, inv = rsqrtf(var+1e-5f);
  pl[t] = (v0-mu)*inv*g[t] + be[t];
  pl[t+256] = (v1-mu)*inv*g[t+256] + be[t+256];
  __syncthreads();
  float lg[4];
  #pragma unroll
  for (int q = 0; q < 4; ++q) {
    int c = t + (q<<8);
    float a = -1e30f;
    if (c < NC) {
      a = bm[c];
      #pragma unroll 8
      for (int k = 0; k < 512; ++k) a += pl[k]*Wm[(size_t)k*NC + c];
    }
    lg[q] = a;
  }
  float mx = fmaxf(fmaxf(lg[0],lg[1]), fmaxf(lg[2],lg[3]));
  for (int o = 32; o; o >>= 1) mx = fmaxf(mx, __shfl_down(mx,o));
  __syncthreads();
  if ((t&63)==0) rb[t>>6] = mx;
  __syncthreads();
  float MX = fmaxf(fmaxf(rb[0],rb[1]), fmaxf(rb[2],rb[3]));
  float es = 0.f, ev[4];
  #pragma unroll
  for (int q = 0; q < 4; ++q) {
    int c = t + (q<<8);
    ev[q] = (c < NC) ? __expf(lg[q]-MX) : 0.f;
    es += ev[q];
  }
  for (int o = 32; o; o >>= 1) es += __shfl_down(es,o);
  __syncthreads();
  if ((t&63)==0) rb[4+(t>>6)] = es;
  __syncthreads();
  float SUM = rb[4]+rb[5]+rb[6]+rb[7];
  float rinv = 1.f/SUM;
  #pragma unroll
  for (int q = 0; q < 4; ++q) {
    int c = t + (q<<8);
    if (c < NC) out[(size_t)b*NC + c] = ev[q]*rinv;
  }
}

extern "C" void kernel_launch(void* const* d_in, const int* in_sizes, int n_in,
                              void* d_out, int out_size, void* d_ws, size_t ws_size,
                              hipStream_t stream) {
  const float* img = (const float*)d_in[0];
  const float* lpg = (const float*)d_in[1];
  const float* lpb = (const float*)d_in[2];
  const float* wqw = (const float*)d_in[3];
  const float* wqb = (const float*)d_in[4];
  const float* lqg = (const float*)d_in[5];
  const float* lqb = (const float*)d_in[6];
  const float* wvw = (const float*)d_in[7];
  const float* wvb = (const float*)d_in[8];
  const float* lvg = (const float*)d_in[9];
  const float* lvb = (const float*)d_in[10];
  const float* pos = (const float*)d_in[11];
  const float* mlg = (const float*)d_in[12];
  const float* mlb = (const float*)d_in[13];
  const float* mw  = (const float*)d_in[14];
  const float* mb  = (const float*)d_in[15];
  float* outp = (float*)d_out;

  float* ws = (float*)d_ws;
  size_t off = 0;
  float* x  = ws + off;      off += (size_t)B_*NP*PD;
  float* q  = ws + off;      off += (size_t)B_*NP*DM;
  float* v  = ws + off;      off += (size_t)B_*NP*DM;
  size_t matp = (size_t)B_*MAT + 256;  // +tail pad for benign overrun reads
  float* A  = ws + off;      off += matp;
  float* p  = ws + off;      off += matp;
  float* Xa = ws + off;      off += matp;
  float* Xb = ws + off;      off += matp;
  float* T  = ws + off;      off += matp;
  float* w  = ws + off;      off += (size_t)B_*NP;
  float* pooled = ws + off;  off += (size_t)B_*DM;
  if (ws_size < off * sizeof(float)) return;  // workspace too small -> fail loudly

  k_patchify<<<dim3(B_*NP), 256, 0, stream>>>(img, lpg, lpb, pos, x);
  k_gemm768<<<dim3(8, 98), 256, 0, stream>>>(x, wqw, wqb, q);
  k_gemm768<<<dim3(8, 98), 256, 0, stream>>>(x, wvw, wvb, v);
  k_lnrow<<<dim3(B_*NP), 256, 0, stream>>>(q, lqg, lqb, 1.0f);
  k_lnrow<<<dim3(B_*NP), 256, 0, stream>>>(v, lvg, lvb, 1.0f/196.0f);
  // A = 2 V V^T + I ;  p = -2 Q V^T + 1/196
  k_bgemm_nt<<<dim3(7,7,B_), 256, 0, stream>>>(v, v, A, 2.0f, 1.0f, 0.0f);
  k_bgemm_nt<<<dim3(7,7,B_), 256, 0, stream>>>(q, v, p, -2.0f, 0.0f, 1.0f/196.0f);
  // Minv via Newton-Schulz; ninf(Q1) ~= 0.26 meas-est -> rho0^(2^4) << 1e-9 even at ninf=1
  k_nsinit<<<dim3(B_), 256, 0, stream>>>(A, Xa);
  float* cur = Xa; float* nxt = Xb;
  for (int it = 0; it < 4; ++it) {
    k_bgemm_nn<<<dim3(4,4,B_), 256, 0, stream>>>(A, cur, T, 1.0f, nullptr, 0.0f);
    k_bgemm_nn<<<dim3(4,4,B_), 256, 0, stream>>>(cur, T, nxt, -1.0f, cur, 2.0f);
    float* tmp = cur; cur = nxt; nxt = tmp;
  }
  hipMemsetAsync(w, 0, (size_t)B_*NP*sizeof(float), stream);
  k_admm2<<<dim3(13*B_), 256, 0, stream>>>(cur, p, w);
  k_pooled<<<dim3(2, B_), 256, 0, stream>>>(w, v, pooled);
  k_head<<<dim3(B_), 256, 0, stream>>>(pooled, mlg, mlb, mw, mb, outp);
}

// Round 3
// 1319.968 us; speedup vs baseline: 1.3897x; 1.0166x over previous
//
#include <hip/hip_runtime.h>

#define B_ 32
#define NP 196
#define PD 768
#define DM 512
#define NC 1000
#define MAT (NP*NP)

// ---------------- patchify + LN + pos ----------------
__global__ __launch_bounds__(256) void k_patchify(
    const float* __restrict__ img, const float* __restrict__ g,
    const float* __restrict__ be, const float* __restrict__ pos,
    float* __restrict__ x) {
  int bn = blockIdx.x;
  int b = bn / NP, n = bn % NP;
  int gh = n / 14, gw = n % 14;
  int t = threadIdx.x;
  float vals[3]; float s = 0.f, ss = 0.f;
  #pragma unroll
  for (int k = 0; k < 3; ++k) {
    int e = t + (k << 8);
    int inner = e & 255;
    int ph = inner >> 4, pw = inner & 15;
    float v = img[((b*3 + k)*224 + gh*16 + ph)*224 + gw*16 + pw];
    vals[k] = v; s += v; ss += v*v;
  }
  __shared__ float rb[8];
  for (int o = 32; o; o >>= 1) { s += __shfl_down(s,o); ss += __shfl_down(ss,o); }
  if ((t & 63) == 0) { rb[t>>6] = s; rb[4+(t>>6)] = ss; }
  __syncthreads();
  float S = rb[0]+rb[1]+rb[2]+rb[3], SS = rb[4]+rb[5]+rb[6]+rb[7];
  float mu = S * (1.f/768.f);
  float var = SS * (1.f/768.f) - mu*mu;
  float inv = rsqrtf(var + 1e-5f);
  #pragma unroll
  for (int k = 0; k < 3; ++k) {
    int e = t + (k << 8);
    x[(size_t)bn*PD + e] = (vals[k]-mu)*inv*g[e] + be[e] + pos[n*PD + e];
  }
}

// ---------------- GEMM M=6272 K=768 N=512 (64x64 tile, 4x4/thread) ----------------
__global__ __launch_bounds__(256) void k_gemm768(
    const float* __restrict__ A, const float* __restrict__ W,
    const float* __restrict__ bias, float* __restrict__ out) {
  __shared__ __align__(16) float As[16][68];
  __shared__ __align__(16) float Bs[16][64];
  int n0 = blockIdx.x * 64, m0 = blockIdx.y * 64;
  int t = threadIdx.x, tx = t & 15, ty = t >> 4;
  int alr = t >> 2, alc = (t & 3) << 2;   // A tile: 64 rows x 16 k
  int blr = t >> 4, blc = (t & 15) << 2;  // W tile: 16 k x 64 n
  float acc[4][4] = {};
  for (int k0 = 0; k0 < 768; k0 += 16) {
    float4 av = *reinterpret_cast<const float4*>(&A[(size_t)(m0+alr)*768 + k0 + alc]);
    float4 bv = *reinterpret_cast<const float4*>(&W[(size_t)(k0+blr)*512 + n0 + blc]);
    As[alc+0][alr] = av.x; As[alc+1][alr] = av.y;
    As[alc+2][alr] = av.z; As[alc+3][alr] = av.w;
    *reinterpret_cast<float4*>(&Bs[blr][blc]) = bv;
    __syncthreads();
    #pragma unroll
    for (int kt = 0; kt < 16; ++kt) {
      float a4[4], b4[4];
      *reinterpret_cast<float4*>(a4) = *reinterpret_cast<const float4*>(&As[kt][ty<<2]);
      *reinterpret_cast<float4*>(b4) = *reinterpret_cast<const float4*>(&Bs[kt][tx<<2]);
      #pragma unroll
      for (int i = 0; i < 4; ++i)
        #pragma unroll
        for (int j = 0; j < 4; ++j) acc[i][j] += a4[i]*b4[j];
    }
    __syncthreads();
  }
  float4 bvv = *reinterpret_cast<const float4*>(&bias[n0 + (tx<<2)]);
  float bb4[4] = {bvv.x, bvv.y, bvv.z, bvv.w};
  #pragma unroll
  for (int i = 0; i < 4; ++i) {
    float4 o;
    o.x = acc[i][0]+bb4[0]; o.y = acc[i][1]+bb4[1];
    o.z = acc[i][2]+bb4[2]; o.w = acc[i][3]+bb4[3];
    *reinterpret_cast<float4*>(&out[(size_t)(m0+(ty<<2)+i)*512 + n0 + (tx<<2)]) = o;
  }
}

// ---------------- row LayerNorm over 512 (+scale) ----------------
__global__ __launch_bounds__(256) void k_lnrow(
    float* __restrict__ X, const float* __restrict__ g,
    const float* __restrict__ be, float scale) {
  int r = blockIdx.x, t = threadIdx.x;
  float v0 = X[(size_t)r*512 + t], v1 = X[(size_t)r*512 + 256 + t];
  float s = v0+v1, ss = v0*v0+v1*v1;
  __shared__ float rb[8];
  for (int o = 32; o; o >>= 1) { s += __shfl_down(s,o); ss += __shfl_down(ss,o); }
  if ((t&63)==0) { rb[t>>6]=s; rb[4+(t>>6)]=ss; }
  __syncthreads();
  float S = rb[0]+rb[1]+rb[2]+rb[3], SS = rb[4]+rb[5]+rb[6]+rb[7];
  float mu = S*(1.f/512.f), var = SS*(1.f/512.f)-mu*mu;
  float inv = rsqrtf(var+1e-5f);
  X[(size_t)r*512+t]     = ((v0-mu)*inv*g[t]+be[t])*scale;
  X[(size_t)r*512+256+t] = ((v1-mu)*inv*g[t+256]+be[t+256])*scale;
}

// ---------------- batched NT gemm, 64x64 tile: out = alpha*X@Y^T + diag + const ----------------
__global__ __launch_bounds__(256) void k_bgemm_nt64(
    const float* __restrict__ X, const float* __restrict__ Y,
    float* __restrict__ out, float alpha, float diagAdd, float cAdd) {
  int b = blockIdx.z;
  int c0 = blockIdx.x * 64, r0 = blockIdx.y * 64;
  __shared__ __align__(16) float Xs[16][68];
  __shared__ __align__(16) float Ys[16][68];
  int t = threadIdx.x, tx = t & 15, ty = t >> 4;
  int lr = t >> 2, lc4 = (t & 3) << 2;    // 64 rows x 16 k per stage
  const float* Xb = X + (size_t)b*NP*512;
  const float* Yb = Y + (size_t)b*NP*512;
  float acc[4][4] = {};
  int xr = min(r0 + lr, NP-1), yr = min(c0 + lr, NP-1);
  for (int k0 = 0; k0 < 512; k0 += 16) {
    float4 xv = *reinterpret_cast<const float4*>(&Xb[(size_t)xr*512 + k0 + lc4]);
    float4 yv = *reinterpret_cast<const float4*>(&Yb[(size_t)yr*512 + k0 + lc4]);
    Xs[lc4+0][lr] = xv.x; Xs[lc4+1][lr] = xv.y;
    Xs[lc4+2][lr] = xv.z; Xs[lc4+3][lr] = xv.w;
    Ys[lc4+0][lr] = yv.x; Ys[lc4+1][lr] = yv.y;
    Ys[lc4+2][lr] = yv.z; Ys[lc4+3][lr] = yv.w;
    __syncthreads();
    #pragma unroll
    for (int kt = 0; kt < 16; ++kt) {
      float a4[4], b4[4];
      *reinterpret_cast<float4*>(a4) = *reinterpret_cast<const float4*>(&Xs[kt][ty<<2]);
      *reinterpret_cast<float4*>(b4) = *reinterpret_cast<const float4*>(&Ys[kt][tx<<2]);
      #pragma unroll
      for (int i = 0; i < 4; ++i)
        #pragma unroll
        for (int j = 0; j < 4; ++j) acc[i][j] += a4[i]*b4[j];
    }
    __syncthreads();
  }
  #pragma unroll
  for (int i = 0; i < 4; ++i) {
    int r = r0 + (ty<<2) + i; if (r >= NP) continue;
    #pragma unroll
    for (int j = 0; j < 4; ++j) {
      int c = c0 + (tx<<2) + j; if (c >= NP) continue;
      out[((size_t)b*NP + r)*NP + c] = alpha*acc[i][j] + cAdd + (r==c ? diagAdd : 0.f);
    }
  }
}

// ---------------- Newton-Schulz init: ninf bound + X0 = c*I ----------------
__global__ __launch_bounds__(256) void k_nsinit(
    const float* __restrict__ A, float* __restrict__ X) {
  int b = blockIdx.x, t = threadIdx.x;
  const float* Ab = A + (size_t)b*MAT;
  __shared__ float sm[256];
  float lm = 0.f;
  if (t < NP) {
    float s = 0.f;
    for (int j = 0; j < NP; ++j) {
      float v = Ab[t*NP + j];
      if (j == t) v -= 1.f;
      s += fabsf(v);
    }
    lm = s;
  }
  sm[t] = lm; __syncthreads();
  for (int o = 128; o; o >>= 1) { if (t < o) sm[t] = fmaxf(sm[t], sm[t+o]); __syncthreads(); }
  float cc = 2.f / (2.f + sm[0]);
  float* Xb = X + (size_t)b*MAT;
  for (int idx = t; idx < MAT; idx += 256)
    Xb[idx] = (idx % (NP+1) == 0) ? cc : 0.f;
}

// ---------------- batched NN gemm (196x196x196): out = alpha*L@R (+ addScale*Add) ----------------
__global__ __launch_bounds__(256) void k_bgemm_nn(
    const float* __restrict__ L, const float* __restrict__ R,
    float* __restrict__ out, float alpha,
    const float* __restrict__ Add, float addScale) {
  int b = blockIdx.z;
  int c0 = blockIdx.x * 64, r0 = blockIdx.y * 64;
  __shared__ __align__(16) float Ls[16][68];
  __shared__ __align__(16) float Rs[16][64];
  int t = threadIdx.x, tx = t & 15, ty = t >> 4;
  int alr = t >> 2, alc = (t & 3) << 2;   // L: 64 rows x 16 k
  int blr = t >> 4, blc = (t & 15) << 2;  // R: 16 k x 64 cols
  const float* Lb = L + (size_t)b*MAT;
  const float* Rb = R + (size_t)b*MAT;
  float acc[4][4] = {};
  int lrow = min(r0 + alr, NP-1);
  for (int k0 = 0; k0 < NP; k0 += 16) {
    float4 lv = {0.f,0.f,0.f,0.f};
    if (k0 + alc < NP) lv = *reinterpret_cast<const float4*>(&Lb[(size_t)lrow*NP + k0 + alc]);
    float4 rv = {0.f,0.f,0.f,0.f};
    if (k0 + blr < NP) rv = *reinterpret_cast<const float4*>(&Rb[(size_t)(k0+blr)*NP + c0 + blc]);
    Ls[alc+0][alr] = lv.x; Ls[alc+1][alr] = lv.y;
    Ls[alc+2][alr] = lv.z; Ls[alc+3][alr] = lv.w;
    *reinterpret_cast<float4*>(&Rs[blr][blc]) = rv;
    __syncthreads();
    #pragma unroll
    for (int kt = 0; kt < 16; ++kt) {
      float a4[4], b4[4];
      *reinterpret_cast<float4*>(a4) = *reinterpret_cast<const float4*>(&Ls[kt][ty<<2]);
      *reinterpret_cast<float4*>(b4) = *reinterpret_cast<const float4*>(&Rs[kt][tx<<2]);
      #pragma unroll
      for (int i = 0; i < 4; ++i)
        #pragma unroll
        for (int j = 0; j < 4; ++j) acc[i][j] += a4[i]*b4[j];
    }
    __syncthreads();
  }
  #pragma unroll
  for (int i = 0; i < 4; ++i) {
    int r = r0 + (ty<<2) + i; if (r >= NP) continue;
    #pragma unroll
    for (int j = 0; j < 4; ++j) {
      int c = c0 + (tx<<2) + j; if (c >= NP) continue;
      float v = alpha * acc[i][j];
      if (Add) v += addScale * Add[((size_t)b*NP + r)*NP + c];
      out[((size_t)b*NP + r)*NP + c] = v;
    }
  }
}

// ---------------- fused 50-iter ADMM v3 ----------------
// 800 blocks: 25 tiles x 8 tokens x 32 batches. 256 thr = 8 ty x 32 tx.
// Thread (ty,tx<28) owns token n0+ty, m-chunk [7tx,7tx+7): z,u,p in registers.
// ty also owns a 4-aligned j-range (ty0:28, else 24) of the 196-reduction.
// rsT[n][m] layout: all LDS access stride-7 across lanes -> conflict-free.
// Minv streamed from L2 (batch = bid&31 -> 4 batches pinned per XCD L2).
__global__ __launch_bounds__(256, 3) void k_admm3(
    const float* __restrict__ Minv, const float* __restrict__ P,
    float* __restrict__ w) {
  int bid = blockIdx.x;
  int b = bid & 31;
  int tile = bid >> 5;               // 0..24 (tokens 192..199 in last: 4 pad)
  int n0 = tile * 8;
  int t = threadIdx.x;
  int tx = t & 31, ty = t >> 5, wv = t >> 6;
  bool act = (tx < 28);
  int m0 = 7 * tx;

  __shared__ __align__(16) float rsT[8][200];   // rhs, [token][m]
  __shared__ float rp[4][8][200];               // per-wave j-partials

  const float* Mb = Minv + (size_t)b * MAT;
  const float* Pb = P + (size_t)b * MAT;

  int nq = (ty == 0) ? 7 : 6;                       // quads of 4 j's
  int jstart = (ty == 0) ? 0 : 28 + 24 * (ty - 1);  // 4-aligned starts

  float z[7], u[7], pr[7];
  #pragma unroll
  for (int k = 0; k < 7; ++k) { z[k] = 0.f; u[k] = 0.f; pr[k] = 0.f; }

  int ng = min(n0 + ty, NP - 1);                    // pad dups token 195 (masked later)
  if (act) {
    const float* prow = Pb + (size_t)ng * NP + m0;
    #pragma unroll
    for (int k = 0; k < 7; ++k) pr[k] = prow[k];
    #pragma unroll
    for (int k = 0; k < 7; ++k) rsT[ty][m0 + k] = -pr[k];  // rhs0 = -p
  }
  __syncthreads();

  for (int it = 0; it < 50; ++it) {
    float acc[8][7];
    if (act) {
      #pragma unroll
      for (int n = 0; n < 8; ++n)
        #pragma unroll
        for (int k = 0; k < 7; ++k) acc[n][k] = 0.f;
      const float* mrow = Mb + (size_t)jstart * NP + m0;
      for (int q = 0; q < nq; ++q) {
        int j = jstart + (q << 2);
        float4 rr[8];
        #pragma unroll
        for (int n = 0; n < 8; ++n)
          rr[n] = *reinterpret_cast<const float4*>(&rsT[n][j]);
        float mv[4][7];
        {
          const float* mr = mrow;
          #pragma unroll
          for (int jj = 0; jj < 4; ++jj) {
            #pragma unroll
            for (int k = 0; k < 7; ++k) mv[jj][k] = mr[k];
            mr += NP;
          }
        }
        #pragma unroll
        for (int jj = 0; jj < 4; ++jj)
          #pragma unroll
          for (int n = 0; n < 8; ++n) {
            float rv = (jj == 0) ? rr[n].x : (jj == 1) ? rr[n].y
                     : (jj == 2) ? rr[n].z : rr[n].w;
            #pragma unroll
            for (int k = 0; k < 7; ++k)
              acc[n][k] = fmaf(mv[jj][k], rv, acc[n][k]);
          }
        mrow += 4 * NP;
      }
      // combine the two half-wave j-ranges
      #pragma unroll
      for (int n = 0; n < 8; ++n)
        #pragma unroll
        for (int k = 0; k < 7; ++k)
          acc[n][k] += __shfl_xor(acc[n][k], 32, 64);
      if ((t & 63) < 32) {
        #pragma unroll
        for (int n = 0; n < 8; ++n)
          #pragma unroll
          for (int k = 0; k < 7; ++k)
            rp[wv][n][m0 + k] = acc[n][k];
      }
    }
    __syncthreads();
    if (act) {
      #pragma unroll
      for (int k = 0; k < 7; ++k) {
        int m = m0 + k;
        float x = rp[0][ty][m] + rp[1][ty][m] + rp[2][ty][m] + rp[3][ty][m];
        float xpu = x + u[k];
        float zz = fminf(fmaxf(xpu, 0.f), 1.f);
        u[k] = xpu - zz;
        z[k] = zz;
        rsT[ty][m] = zz - u[k] - pr[k];
      }
    }
    __syncthreads();
  }

  // coeffs = z / (sum z + 1e-10); w[b][m] += mean_n coeffs  (z>=0 after clip)
  float s = 0.f;
  #pragma unroll
  for (int k = 0; k < 7; ++k) s += z[k];
  #pragma unroll
  for (int o = 16; o; o >>= 1) s += __shfl_xor(s, o, 64);  // within 32-lane ty group
  float inv = 1.f / (s + 1e-10f);
  if (n0 + ty >= NP) inv = 0.f;   // mask pad tokens
  if (act) {
    #pragma unroll
    for (int k = 0; k < 7; ++k)
      atomicAdd(&w[b*NP + m0 + k], z[k] * inv * (1.f/196.f));
  }
}

// ---------------- pooled[b,d] = sum_m w[b,m] V[b,m,d] ----------------
__global__ __launch_bounds__(256) void k_pooled(
    const float* __restrict__ w, const float* __restrict__ V,
    float* __restrict__ pooled) {
  int b = blockIdx.y, t = threadIdx.x;
  int d = blockIdx.x * 256 + t;
  __shared__ float ws_[NP];
  if (t < NP) ws_[t] = w[b*NP + t];
  __syncthreads();
  float acc = 0.f;
  for (int m = 0; m < NP; ++m)
    acc += ws_[m] * V[((size_t)b*NP + m)*512 + d];
  pooled[(size_t)b*512 + d] = acc;
}

// ---------------- LN + 512x1000 head + softmax ----------------
__global__ __launch_bounds__(256) void k_head(
    const float* __restrict__ pooled, const float* __restrict__ g,
    const float* __restrict__ be, const float* __restrict__ Wm,
    const float* __restrict__ bm, float* __restrict__ out) {
  int b = blockIdx.x, t = threadIdx.x;
  __shared__ float pl[512];
  __shared__ float rb[8];
  float v0 = pooled[(size_t)b*512 + t], v1 = pooled[(size_t)b*512 + 256 + t];
  float s = v0+v1, ss = v0*v0+v1*v1;
  for (int o = 32; o; o >>= 1) { s += __shfl_down(s,o); ss += __shfl_down(ss,o); }
  if ((t&63)==0) { rb[t>>6]=s; rb[4+(t>>6)]=ss; }
  __syncthreads();
  float S = rb[0]+rb[1]+rb[2]+rb[3], SS = rb[4]+rb[5]+rb[6]+rb[7];
  float mu = S*(1.f/512.f), var = SS*(1.f/512.f)-mu*mu, inv = rsqrtf(var+1e-5f);
  pl[t] = (v0-mu)*inv*g[t] + be[t];
  pl[t+256] = (v1-mu)*inv*g[t+256] + be[t+256];
  __syncthreads();
  float lg[4];
  #pragma unroll
  for (int q = 0; q < 4; ++q) {
    int c = t + (q<<8);
    float a = -1e30f;
    if (c < NC) {
      a = bm[c];
      #pragma unroll 8
      for (int k = 0; k < 512; ++k) a += pl[k]*Wm[(size_t)k*NC + c];
    }
    lg[q] = a;
  }
  float mx = fmaxf(fmaxf(lg[0],lg[1]), fmaxf(lg[2],lg[3]));
  for (int o = 32; o; o >>= 1) mx = fmaxf(mx, __shfl_down(mx,o));
  __syncthreads();
  if ((t&63)==0) rb[t>>6] = mx;
  __syncthreads();
  float MX = fmaxf(fmaxf(rb[0],rb[1]), fmaxf(rb[2],rb[3]));
  float es = 0.f, ev[4];
  #pragma unroll
  for (int q = 0; q < 4; ++q) {
    int c = t + (q<<8);
    ev[q] = (c < NC) ? __expf(lg[q]-MX) : 0.f;
    es += ev[q];
  }
  for (int o = 32; o; o >>= 1) es += __shfl_down(es,o);
  __syncthreads();
  if ((t&63)==0) rb[4+(t>>6)] = es;
  __syncthreads();
  float SUM = rb[4]+rb[5]+rb[6]+rb[7];
  float rinv = 1.f/SUM;
  #pragma unroll
  for (int q = 0; q < 4; ++q) {
    int c = t + (q<<8);
    if (c < NC) out[(size_t)b*NC + c] = ev[q]*rinv;
  }
}

extern "C" void kernel_launch(void* const* d_in, const int* in_sizes, int n_in,
                              void* d_out, int out_size, void* d_ws, size_t ws_size,
                              hipStream_t stream) {
  const float* img = (const float*)d_in[0];
  const float* lpg = (const float*)d_in[1];
  const float* lpb = (const float*)d_in[2];
  const float* wqw = (const float*)d_in[3];
  const float* wqb = (const float*)d_in[4];
  const float* lqg = (const float*)d_in[5];
  const float* lqb = (const float*)d_in[6];
  const float* wvw = (const float*)d_in[7];
  const float* wvb = (const float*)d_in[8];
  const float* lvg = (const float*)d_in[9];
  const float* lvb = (const float*)d_in[10];
  const float* pos = (const float*)d_in[11];
  const float* mlg = (const float*)d_in[12];
  const float* mlb = (const float*)d_in[13];
  const float* mw  = (const float*)d_in[14];
  const float* mb  = (const float*)d_in[15];
  float* outp = (float*)d_out;

  float* ws = (float*)d_ws;
  size_t off = 0;
  float* x  = ws + off;      off += (size_t)B_*NP*PD;
  float* q  = ws + off;      off += (size_t)B_*NP*DM;
  float* v  = ws + off;      off += (size_t)B_*NP*DM;
  size_t matp = (size_t)B_*MAT + 256;  // +tail pad for benign overrun reads
  float* A  = ws + off;      off += matp;
  float* p  = ws + off;      off += matp;
  float* Xa = ws + off;      off += matp;
  float* Xb = ws + off;      off += matp;
  float* T  = ws + off;      off += matp;
  float* w  = ws + off;      off += (size_t)B_*NP;
  float* pooled = ws + off;  off += (size_t)B_*DM;
  if (ws_size < off * sizeof(float)) return;  // workspace too small -> fail loudly

  k_patchify<<<dim3(B_*NP), 256, 0, stream>>>(img, lpg, lpb, pos, x);
  k_gemm768<<<dim3(8, 98), 256, 0, stream>>>(x, wqw, wqb, q);
  k_gemm768<<<dim3(8, 98), 256, 0, stream>>>(x, wvw, wvb, v);
  k_lnrow<<<dim3(B_*NP), 256, 0, stream>>>(q, lqg, lqb, 1.0f);
  k_lnrow<<<dim3(B_*NP), 256, 0, stream>>>(v, lvg, lvb, 1.0f/196.0f);
  // A = 2 V V^T + I ;  p = -2 Q V^T + 1/196
  k_bgemm_nt64<<<dim3(4,4,B_), 256, 0, stream>>>(v, v, A, 2.0f, 1.0f, 0.0f);
  k_bgemm_nt64<<<dim3(4,4,B_), 256, 0, stream>>>(q, v, p, -2.0f, 0.0f, 1.0f/196.0f);
  // Minv via Newton-Schulz (4 iters: rho0^16 << 1e-8 even at ninf=1)
  k_nsinit<<<dim3(B_), 256, 0, stream>>>(A, Xa);
  float* cur = Xa; float* nxt = Xb;
  for (int it = 0; it < 4; ++it) {
    k_bgemm_nn<<<dim3(4,4,B_), 256, 0, stream>>>(A, cur, T, 1.0f, nullptr, 0.0f);
    k_bgemm_nn<<<dim3(4,4,B_), 256, 0, stream>>>(cur, T, nxt, -1.0f, cur, 2.0f);
    float* tmp = cur; cur = nxt; nxt = tmp;
  }
  hipMemsetAsync(w, 0, (size_t)B_*NP*sizeof(float), stream);
  k_admm3<<<dim3(25*B_), 256, 0, stream>>>(cur, p, w);
  k_pooled<<<dim3(2, B_), 256, 0, stream>>>(w, v, pooled);
  k_head<<<dim3(B_), 256, 0, stream>>>(pooled, mlg, mlb, mw, mb, outp);
}

// Round 4
// 1309.507 us; speedup vs baseline: 1.4008x; 1.0080x over previous
//
#include <hip/hip_runtime.h>

#define B_ 32
#define NP 196
#define PD 768
#define DM 512
#define NC 1000
#define MAT (NP*NP)

// ---------------- patchify + LN + pos ----------------
__global__ __launch_bounds__(256) void k_patchify(
    const float* __restrict__ img, const float* __restrict__ g,
    const float* __restrict__ be, const float* __restrict__ pos,
    float* __restrict__ x) {
  int bn = blockIdx.x;
  int b = bn / NP, n = bn % NP;
  int gh = n / 14, gw = n % 14;
  int t = threadIdx.x;
  float vals[3]; float s = 0.f, ss = 0.f;
  #pragma unroll
  for (int k = 0; k < 3; ++k) {
    int e = t + (k << 8);
    int inner = e & 255;
    int ph = inner >> 4, pw = inner & 15;
    float v = img[((b*3 + k)*224 + gh*16 + ph)*224 + gw*16 + pw];
    vals[k] = v; s += v; ss += v*v;
  }
  __shared__ float rb[8];
  for (int o = 32; o; o >>= 1) { s += __shfl_down(s,o); ss += __shfl_down(ss,o); }
  if ((t & 63) == 0) { rb[t>>6] = s; rb[4+(t>>6)] = ss; }
  __syncthreads();
  float S = rb[0]+rb[1]+rb[2]+rb[3], SS = rb[4]+rb[5]+rb[6]+rb[7];
  float mu = S * (1.f/768.f);
  float var = SS * (1.f/768.f) - mu*mu;
  float inv = rsqrtf(var + 1e-5f);
  #pragma unroll
  for (int k = 0; k < 3; ++k) {
    int e = t + (k << 8);
    x[(size_t)bn*PD + e] = (vals[k]-mu)*inv*g[e] + be[e] + pos[n*PD + e];
  }
}

// ---------------- GEMM M=6272 K=768 N=512 (64x64 tile, 4x4/thread) ----------------
__global__ __launch_bounds__(256) void k_gemm768(
    const float* __restrict__ A, const float* __restrict__ W,
    const float* __restrict__ bias, float* __restrict__ out) {
  __shared__ __align__(16) float As[16][68];
  __shared__ __align__(16) float Bs[16][64];
  int n0 = blockIdx.x * 64, m0 = blockIdx.y * 64;
  int t = threadIdx.x, tx = t & 15, ty = t >> 4;
  int alr = t >> 2, alc = (t & 3) << 2;   // A tile: 64 rows x 16 k
  int blr = t >> 4, blc = (t & 15) << 2;  // W tile: 16 k x 64 n
  float acc[4][4] = {};
  for (int k0 = 0; k0 < 768; k0 += 16) {
    float4 av = *reinterpret_cast<const float4*>(&A[(size_t)(m0+alr)*768 + k0 + alc]);
    float4 bv = *reinterpret_cast<const float4*>(&W[(size_t)(k0+blr)*512 + n0 + blc]);
    As[alc+0][alr] = av.x; As[alc+1][alr] = av.y;
    As[alc+2][alr] = av.z; As[alc+3][alr] = av.w;
    *reinterpret_cast<float4*>(&Bs[blr][blc]) = bv;
    __syncthreads();
    #pragma unroll
    for (int kt = 0; kt < 16; ++kt) {
      float a4[4], b4[4];
      *reinterpret_cast<float4*>(a4) = *reinterpret_cast<const float4*>(&As[kt][ty<<2]);
      *reinterpret_cast<float4*>(b4) = *reinterpret_cast<const float4*>(&Bs[kt][tx<<2]);
      #pragma unroll
      for (int i = 0; i < 4; ++i)
        #pragma unroll
        for (int j = 0; j < 4; ++j) acc[i][j] += a4[i]*b4[j];
    }
    __syncthreads();
  }
  float4 bvv = *reinterpret_cast<const float4*>(&bias[n0 + (tx<<2)]);
  float bb4[4] = {bvv.x, bvv.y, bvv.z, bvv.w};
  #pragma unroll
  for (int i = 0; i < 4; ++i) {
    float4 o;
    o.x = acc[i][0]+bb4[0]; o.y = acc[i][1]+bb4[1];
    o.z = acc[i][2]+bb4[2]; o.w = acc[i][3]+bb4[3];
    *reinterpret_cast<float4*>(&out[(size_t)(m0+(ty<<2)+i)*512 + n0 + (tx<<2)]) = o;
  }
}

// ---------------- row LayerNorm over 512 (+scale) ----------------
__global__ __launch_bounds__(256) void k_lnrow(
    float* __restrict__ X, const float* __restrict__ g,
    const float* __restrict__ be, float scale) {
  int r = blockIdx.x, t = threadIdx.x;
  float v0 = X[(size_t)r*512 + t], v1 = X[(size_t)r*512 + 256 + t];
  float s = v0+v1, ss = v0*v0+v1*v1;
  __shared__ float rb[8];
  for (int o = 32; o; o >>= 1) { s += __shfl_down(s,o); ss += __shfl_down(ss,o); }
  if ((t&63)==0) { rb[t>>6]=s; rb[4+(t>>6)]=ss; }
  __syncthreads();
  float S = rb[0]+rb[1]+rb[2]+rb[3], SS = rb[4]+rb[5]+rb[6]+rb[7];
  float mu = S*(1.f/512.f), var = SS*(1.f/512.f)-mu*mu;
  float inv = rsqrtf(var+1e-5f);
  X[(size_t)r*512+t]     = ((v0-mu)*inv*g[t]+be[t])*scale;
  X[(size_t)r*512+256+t] = ((v1-mu)*inv*g[t+256]+be[t+256])*scale;
}

// ---------------- batched NT gemm, 64x64 tile: out = alpha*X@Y^T + diag + const ----------------
__global__ __launch_bounds__(256) void k_bgemm_nt64(
    const float* __restrict__ X, const float* __restrict__ Y,
    float* __restrict__ out, float alpha, float diagAdd, float cAdd) {
  int b = blockIdx.z;
  int c0 = blockIdx.x * 64, r0 = blockIdx.y * 64;
  __shared__ __align__(16) float Xs[16][68];
  __shared__ __align__(16) float Ys[16][68];
  int t = threadIdx.x, tx = t & 15, ty = t >> 4;
  int lr = t >> 2, lc4 = (t & 3) << 2;    // 64 rows x 16 k per stage
  const float* Xb = X + (size_t)b*NP*512;
  const float* Yb = Y + (size_t)b*NP*512;
  float acc[4][4] = {};
  int xr = min(r0 + lr, NP-1), yr = min(c0 + lr, NP-1);
  for (int k0 = 0; k0 < 512; k0 += 16) {
    float4 xv = *reinterpret_cast<const float4*>(&Xb[(size_t)xr*512 + k0 + lc4]);
    float4 yv = *reinterpret_cast<const float4*>(&Yb[(size_t)yr*512 + k0 + lc4]);
    Xs[lc4+0][lr] = xv.x; Xs[lc4+1][lr] = xv.y;
    Xs[lc4+2][lr] = xv.z; Xs[lc4+3][lr] = xv.w;
    Ys[lc4+0][lr] = yv.x; Ys[lc4+1][lr] = yv.y;
    Ys[lc4+2][lr] = yv.z; Ys[lc4+3][lr] = yv.w;
    __syncthreads();
    #pragma unroll
    for (int kt = 0; kt < 16; ++kt) {
      float a4[4], b4[4];
      *reinterpret_cast<float4*>(a4) = *reinterpret_cast<const float4*>(&Xs[kt][ty<<2]);
      *reinterpret_cast<float4*>(b4) = *reinterpret_cast<const float4*>(&Ys[kt][tx<<2]);
      #pragma unroll
      for (int i = 0; i < 4; ++i)
        #pragma unroll
        for (int j = 0; j < 4; ++j) acc[i][j] += a4[i]*b4[j];
    }
    __syncthreads();
  }
  #pragma unroll
  for (int i = 0; i < 4; ++i) {
    int r = r0 + (ty<<2) + i; if (r >= NP) continue;
    #pragma unroll
    for (int j = 0; j < 4; ++j) {
      int c = c0 + (tx<<2) + j; if (c >= NP) continue;
      out[((size_t)b*NP + r)*NP + c] = alpha*acc[i][j] + cAdd + (r==c ? diagAdd : 0.f);
    }
  }
}

// ---------------- Newton-Schulz init: ninf bound + X0 = c*I ----------------
__global__ __launch_bounds__(256) void k_nsinit(
    const float* __restrict__ A, float* __restrict__ X) {
  int b = blockIdx.x, t = threadIdx.x;
  const float* Ab = A + (size_t)b*MAT;
  __shared__ float sm[256];
  float lm = 0.f;
  if (t < NP) {
    float s = 0.f;
    for (int j = 0; j < NP; ++j) {
      float v = Ab[t*NP + j];
      if (j == t) v -= 1.f;
      s += fabsf(v);
    }
    lm = s;
  }
  sm[t] = lm; __syncthreads();
  for (int o = 128; o; o >>= 1) { if (t < o) sm[t] = fmaxf(sm[t], sm[t+o]); __syncthreads(); }
  float cc = 2.f / (2.f + sm[0]);
  float* Xb = X + (size_t)b*MAT;
  for (int idx = t; idx < MAT; idx += 256)
    Xb[idx] = (idx % (NP+1) == 0) ? cc : 0.f;
}

// ---------------- batched NN gemm (196x196x196): out = alpha*L@R (+ addScale*Add) ----------------
__global__ __launch_bounds__(256) void k_bgemm_nn(
    const float* __restrict__ L, const float* __restrict__ R,
    float* __restrict__ out, float alpha,
    const float* __restrict__ Add, float addScale) {
  int b = blockIdx.z;
  int c0 = blockIdx.x * 64, r0 = blockIdx.y * 64;
  __shared__ __align__(16) float Ls[16][68];
  __shared__ __align__(16) float Rs[16][64];
  int t = threadIdx.x, tx = t & 15, ty = t >> 4;
  int alr = t >> 2, alc = (t & 3) << 2;   // L: 64 rows x 16 k
  int blr = t >> 4, blc = (t & 15) << 2;  // R: 16 k x 64 cols
  const float* Lb = L + (size_t)b*MAT;
  const float* Rb = R + (size_t)b*MAT;
  float acc[4][4] = {};
  int lrow = min(r0 + alr, NP-1);
  for (int k0 = 0; k0 < NP; k0 += 16) {
    float4 lv = {0.f,0.f,0.f,0.f};
    if (k0 + alc < NP) lv = *reinterpret_cast<const float4*>(&Lb[(size_t)lrow*NP + k0 + alc]);
    float4 rv = {0.f,0.f,0.f,0.f};
    if (k0 + blr < NP) rv = *reinterpret_cast<const float4*>(&Rb[(size_t)(k0+blr)*NP + c0 + blc]);
    Ls[alc+0][alr] = lv.x; Ls[alc+1][alr] = lv.y;
    Ls[alc+2][alr] = lv.z; Ls[alc+3][alr] = lv.w;
    *reinterpret_cast<float4*>(&Rs[blr][blc]) = rv;
    __syncthreads();
    #pragma unroll
    for (int kt = 0; kt < 16; ++kt) {
      float a4[4], b4[4];
      *reinterpret_cast<float4*>(a4) = *reinterpret_cast<const float4*>(&Ls[kt][ty<<2]);
      *reinterpret_cast<float4*>(b4) = *reinterpret_cast<const float4*>(&Rs[kt][tx<<2]);
      #pragma unroll
      for (int i = 0; i < 4; ++i)
        #pragma unroll
        for (int j = 0; j < 4; ++j) acc[i][j] += a4[i]*b4[j];
    }
    __syncthreads();
  }
  #pragma unroll
  for (int i = 0; i < 4; ++i) {
    int r = r0 + (ty<<2) + i; if (r >= NP) continue;
    #pragma unroll
    for (int j = 0; j < 4; ++j) {
      int c = c0 + (tx<<2) + j; if (c >= NP) continue;
      float v = alpha * acc[i][j];
      if (Add) v += addScale * Add[((size_t)b*NP + r)*NP + c];
      out[((size_t)b*NP + r)*NP + c] = v;
    }
  }
}

// ---------------- fused 50-iter ADMM v4 ----------------
// 800 blocks: 25 tiles x 8 tokens x 32 batches. 256 thr = 8 ty x 32 tx.
// Lane tx<28 owns m in {tx+28k, k=0..6} (INTERLEAVED): every Minv global load
// has 28 consecutive lanes on consecutive dwords -> ~2 cache lines per inst
// (was ~12 with blocked ownership -> L1-transaction-bound, VALUBusy 46%).
// j-split: each ty owns quads j=24*ty+4q, q<6 (144+48=192 rows); tail rows
// 192..195 go as float2-pairs to ty6/ty7 (wave-uniform branch, wave 3 only).
// LDS rsT[n][m] stride-28 lane access -> conflict-free. Minv from L2.
__global__ __launch_bounds__(256, 3) void k_admm4(
    const float* __restrict__ Minv, const float* __restrict__ P,
    float* __restrict__ w) {
  int bid = blockIdx.x;
  int b = bid & 31;
  int tile = bid >> 5;               // 0..24 (last tile: tokens 192..199, 4 pad)
  int n0 = tile * 8;
  int t = threadIdx.x;
  int tx = t & 31, ty = t >> 5, wv = t >> 6;
  bool act = (tx < 28);
  int m0 = tx;                       // owned m = tx + 28k

  __shared__ __align__(16) float rsT[8][200];   // rhs, [token][m]
  __shared__ float rp[4][8][200];               // per-wave j-partials

  const float* Mb = Minv + (size_t)b * MAT;
  const float* Pb = P + (size_t)b * MAT;

  int jstart = 24 * ty;

  float z[7], u[7], pr[7];
  #pragma unroll
  for (int k = 0; k < 7; ++k) { z[k] = 0.f; u[k] = 0.f; pr[k] = 0.f; }

  int ng = min(n0 + ty, NP - 1);     // pad dups token 195 (masked later)
  if (act) {
    const float* prow = Pb + (size_t)ng * NP + m0;
    #pragma unroll
    for (int k = 0; k < 7; ++k) pr[k] = prow[28*k];
    #pragma unroll
    for (int k = 0; k < 7; ++k) rsT[ty][m0 + 28*k] = -pr[k];  // rhs0 = -p
  }
  __syncthreads();

  for (int it = 0; it < 50; ++it) {
    float acc[8][7];
    if (act) {
      #pragma unroll
      for (int n = 0; n < 8; ++n)
        #pragma unroll
        for (int k = 0; k < 7; ++k) acc[n][k] = 0.f;
      const float* mrow = Mb + (size_t)jstart * NP + m0;
      #pragma unroll 2
      for (int q = 0; q < 6; ++q) {
        int j = jstart + (q << 2);
        float4 rr[8];
        #pragma unroll
        for (int n = 0; n < 8; ++n)
          rr[n] = *reinterpret_cast<const float4*>(&rsT[n][j]);
        float mv[4][7];
        {
          const float* mr = mrow;
          #pragma unroll
          for (int jj = 0; jj < 4; ++jj) {
            #pragma unroll
            for (int k = 0; k < 7; ++k) mv[jj][k] = mr[28*k];
            mr += NP;
          }
        }
        #pragma unroll
        for (int jj = 0; jj < 4; ++jj)
          #pragma unroll
          for (int n = 0; n < 8; ++n) {
            float rv = (jj == 0) ? rr[n].x : (jj == 1) ? rr[n].y
                     : (jj == 2) ? rr[n].z : rr[n].w;
            #pragma unroll
            for (int k = 0; k < 7; ++k)
              acc[n][k] = fmaf(mv[jj][k], rv, acc[n][k]);
          }
        mrow += 4 * NP;
      }
      // tail rows 192..195: pair per ty6/ty7 (wave-uniform: only wave 3 enters)
      if (ty >= 6) {
        int j2 = 192 + 2 * (ty - 6);
        float2 rr2[8];
        #pragma unroll
        for (int n = 0; n < 8; ++n)
          rr2[n] = *reinterpret_cast<const float2*>(&rsT[n][j2]);
        const float* mr0 = Mb + (size_t)j2 * NP + m0;
        const float* mr1 = mr0 + NP;
        float mv0[7], mv1[7];
        #pragma unroll
        for (int k = 0; k < 7; ++k) { mv0[k] = mr0[28*k]; mv1[k] = mr1[28*k]; }
        #pragma unroll
        for (int n = 0; n < 8; ++n)
          #pragma unroll
          for (int k = 0; k < 7; ++k) {
            acc[n][k] = fmaf(mv0[k], rr2[n].x, acc[n][k]);
            acc[n][k] = fmaf(mv1[k], rr2[n].y, acc[n][k]);
          }
      }
      // combine the two half-wave j-ranges
      #pragma unroll
      for (int n = 0; n < 8; ++n)
        #pragma unroll
        for (int k = 0; k < 7; ++k)
          acc[n][k] += __shfl_xor(acc[n][k], 32, 64);
      if ((t & 63) < 32) {
        #pragma unroll
        for (int n = 0; n < 8; ++n)
          #pragma unroll
          for (int k = 0; k < 7; ++k)
            rp[wv][n][m0 + 28*k] = acc[n][k];
      }
    }
    __syncthreads();
    if (act) {
      #pragma unroll
      for (int k = 0; k < 7; ++k) {
        int m = m0 + 28*k;
        float x = rp[0][ty][m] + rp[1][ty][m] + rp[2][ty][m] + rp[3][ty][m];
        float xpu = x + u[k];
        float zz = fminf(fmaxf(xpu, 0.f), 1.f);
        u[k] = xpu - zz;
        z[k] = zz;
        rsT[ty][m] = zz - u[k] - pr[k];
      }
    }
    __syncthreads();
  }

  // coeffs = z / (sum z + 1e-10); w[b][m] += mean_n coeffs  (z>=0 after clip)
  float s = 0.f;
  #pragma unroll
  for (int k = 0; k < 7; ++k) s += z[k];
  #pragma unroll
  for (int o = 16; o; o >>= 1) s += __shfl_xor(s, o, 64);  // within 32-lane ty group
  float inv = 1.f / (s + 1e-10f);
  if (n0 + ty >= NP) inv = 0.f;   // mask pad tokens
  if (act) {
    #pragma unroll
    for (int k = 0; k < 7; ++k)
      atomicAdd(&w[b*NP + m0 + 28*k], z[k] * inv * (1.f/196.f));
  }
}

// ---------------- pooled[b,d] = sum_m w[b,m] V[b,m,d] ----------------
__global__ __launch_bounds__(256) void k_pooled(
    const float* __restrict__ w, const float* __restrict__ V,
    float* __restrict__ pooled) {
  int b = blockIdx.y, t = threadIdx.x;
  int d = blockIdx.x * 256 + t;
  __shared__ float ws_[NP];
  if (t < NP) ws_[t] = w[b*NP + t];
  __syncthreads();
  float acc = 0.f;
  for (int m = 0; m < NP; ++m)
    acc += ws_[m] * V[((size_t)b*NP + m)*512 + d];
  pooled[(size_t)b*512 + d] = acc;
}

// ---------------- LN + 512x1000 head + softmax ----------------
__global__ __launch_bounds__(256) void k_head(
    const float* __restrict__ pooled, const float* __restrict__ g,
    const float* __restrict__ be, const float* __restrict__ Wm,
    const float* __restrict__ bm, float* __restrict__ out) {
  int b = blockIdx.x, t = threadIdx.x;
  __shared__ float pl[512];
  __shared__ float rb[8];
  float v0 = pooled[(size_t)b*512 + t], v1 = pooled[(size_t)b*512 + 256 + t];
  float s = v0+v1, ss = v0*v0+v1*v1;
  for (int o = 32; o; o >>= 1) { s += __shfl_down(s,o); ss += __shfl_down(ss,o); }
  if ((t&63)==0) { rb[t>>6]=s; rb[4+(t>>6)]=ss; }
  __syncthreads();
  float S = rb[0]+rb[1]+rb[2]+rb[3], SS = rb[4]+rb[5]+rb[6]+rb[7];
  float mu = S*(1.f/512.f), var = SS*(1.f/512.f)-mu*mu, inv = rsqrtf(var+1e-5f);
  pl[t] = (v0-mu)*inv*g[t] + be[t];
  pl[t+256] = (v1-mu)*inv*g[t+256] + be[t+256];
  __syncthreads();
  float lg[4];
  #pragma unroll
  for (int q = 0; q < 4; ++q) {
    int c = t + (q<<8);
    float a = -1e30f;
    if (c < NC) {
      a = bm[c];
      #pragma unroll 8
      for (int k = 0; k < 512; ++k) a += pl[k]*Wm[(size_t)k*NC + c];
    }
    lg[q] = a;
  }
  float mx = fmaxf(fmaxf(lg[0],lg[1]), fmaxf(lg[2],lg[3]));
  for (int o = 32; o; o >>= 1) mx = fmaxf(mx, __shfl_down(mx,o));
  __syncthreads();
  if ((t&63)==0) rb[t>>6] = mx;
  __syncthreads();
  float MX = fmaxf(fmaxf(rb[0],rb[1]), fmaxf(rb[2],rb[3]));
  float es = 0.f, ev[4];
  #pragma unroll
  for (int q = 0; q < 4; ++q) {
    int c = t + (q<<8);
    ev[q] = (c < NC) ? __expf(lg[q]-MX) : 0.f;
    es += ev[q];
  }
  for (int o = 32; o; o >>= 1) es += __shfl_down(es,o);
  __syncthreads();
  if ((t&63)==0) rb[4+(t>>6)] = es;
  __syncthreads();
  float SUM = rb[4]+rb[5]+rb[6]+rb[7];
  float rinv = 1.f/SUM;
  #pragma unroll
  for (int q = 0; q < 4; ++q) {
    int c = t + (q<<8);
    if (c < NC) out[(size_t)b*NC + c] = ev[q]*rinv;
  }
}

extern "C" void kernel_launch(void* const* d_in, const int* in_sizes, int n_in,
                              void* d_out, int out_size, void* d_ws, size_t ws_size,
                              hipStream_t stream) {
  const float* img = (const float*)d_in[0];
  const float* lpg = (const float*)d_in[1];
  const float* lpb = (const float*)d_in[2];
  const float* wqw = (const float*)d_in[3];
  const float* wqb = (const float*)d_in[4];
  const float* lqg = (const float*)d_in[5];
  const float* lqb = (const float*)d_in[6];
  const float* wvw = (const float*)d_in[7];
  const float* wvb = (const float*)d_in[8];
  const float* lvg = (const float*)d_in[9];
  const float* lvb = (const float*)d_in[10];
  const float* pos = (const float*)d_in[11];
  const float* mlg = (const float*)d_in[12];
  const float* mlb = (const float*)d_in[13];
  const float* mw  = (const float*)d_in[14];
  const float* mb  = (const float*)d_in[15];
  float* outp = (float*)d_out;

  float* ws = (float*)d_ws;
  size_t off = 0;
  float* x  = ws + off;      off += (size_t)B_*NP*PD;
  float* q  = ws + off;      off += (size_t)B_*NP*DM;
  float* v  = ws + off;      off += (size_t)B_*NP*DM;
  size_t matp = (size_t)B_*MAT + 256;  // +tail pad for benign overrun reads
  float* A  = ws + off;      off += matp;
  float* p  = ws + off;      off += matp;
  float* Xa = ws + off;      off += matp;
  float* Xb = ws + off;      off += matp;
  float* T  = ws + off;      off += matp;
  float* w  = ws + off;      off += (size_t)B_*NP;
  float* pooled = ws + off;  off += (size_t)B_*DM;
  if (ws_size < off * sizeof(float)) return;  // workspace too small -> fail loudly

  k_patchify<<<dim3(B_*NP), 256, 0, stream>>>(img, lpg, lpb, pos, x);
  k_gemm768<<<dim3(8, 98), 256, 0, stream>>>(x, wqw, wqb, q);
  k_gemm768<<<dim3(8, 98), 256, 0, stream>>>(x, wvw, wvb, v);
  k_lnrow<<<dim3(B_*NP), 256, 0, stream>>>(q, lqg, lqb, 1.0f);
  k_lnrow<<<dim3(B_*NP), 256, 0, stream>>>(v, lvg, lvb, 1.0f/196.0f);
  // A = 2 V V^T + I ;  p = -2 Q V^T + 1/196
  k_bgemm_nt64<<<dim3(4,4,B_), 256, 0, stream>>>(v, v, A, 2.0f, 1.0f, 0.0f);
  k_bgemm_nt64<<<dim3(4,4,B_), 256, 0, stream>>>(q, v, p, -2.0f, 0.0f, 1.0f/196.0f);
  // Minv via Newton-Schulz (4 iters: rho0^16 << 1e-8 even at ninf=1)
  k_nsinit<<<dim3(B_), 256, 0, stream>>>(A, Xa);
  float* cur = Xa; float* nxt = Xb;
  for (int it = 0; it < 4; ++it) {
    k_bgemm_nn<<<dim3(4,4,B_), 256, 0, stream>>>(A, cur, T, 1.0f, nullptr, 0.0f);
    k_bgemm_nn<<<dim3(4,4,B_), 256, 0, stream>>>(cur, T, nxt, -1.0f, cur, 2.0f);
    float* tmp = cur; cur = nxt; nxt = tmp;
  }
  hipMemsetAsync(w, 0, (size_t)B_*NP*sizeof(float), stream);
  k_admm4<<<dim3(25*B_), 256, 0, stream>>>(cur, p, w);
  k_pooled<<<dim3(2, B_), 256, 0, stream>>>(w, v, pooled);
  k_head<<<dim3(B_), 256, 0, stream>>>(pooled, mlg, mlb, mw, mb, outp);
}